// Round 13
// baseline (296.010 us; speedup 1.0000x reference)
//
#include <hip/hip_runtime.h>

typedef unsigned short u16;
typedef __attribute__((ext_vector_type(8))) short short8;
typedef __attribute__((ext_vector_type(4))) float f32x4;

__device__ __forceinline__ float bflo(unsigned u) {
    union { unsigned u; float f; } v; v.u = u << 16; return v.f;
}
__device__ __forceinline__ float bfhi(unsigned u) {
    union { unsigned u; float f; } v; v.u = u & 0xFFFF0000u; return v.f;
}
__device__ __forceinline__ u16 f2bf(float f) {
    union { float f; unsigned u; } v; v.f = f;
    unsigned u = v.u;
    u += 0x7FFFu + ((u >> 16) & 1u);   // round-to-nearest-even
    return (u16)(u >> 16);
}

#define CS 12500   // nodes per LDS-histogram chunk (u32[CS] = 50000 B)

// ---- K1: gemm1 (blocks < GB) || per-block edge counting (blocks >= GB) ----
// Count part: block b owns edges [b*ES,(b+1)*ES); builds LDS histograms over
// 12500-node chunks and writes per-(block,node) counts to ghist[b*N+n] (u16).
// NO global atomics. First count block publishes the dtype flag.
__global__ void k1_gemm_count(const void* __restrict__ Av, const void* __restrict__ W,
                              u16* __restrict__ out, int M, int GB,
                              const int* __restrict__ dst, u16* __restrict__ ghist,
                              int E, int N, int ES, int* __restrict__ flag) {
    constexpr int NOUT = 128;
    __shared__ __align__(16) char ldsbuf[50048];
    int t = threadIdx.x;
    int bid = blockIdx.x;
    if (bid >= GB) {
        int b = bid - GB;
        if (b == 0) {
            __shared__ int c_s;
            if (t == 0) c_s = 0;
            __syncthreads();
            int c = 0;
            for (int i = t; i < 2048; i += 256) {
                int ex = (((const u16*)Av)[2 * i] >> 7) & 0xFF;
                c += (ex >= 160 || ex <= 80) ? 1 : 0;
            }
            atomicAdd(&c_s, c);
            __syncthreads();
            if (t == 0) *flag = (c_s > 64) ? 1 : 0;
        }
        unsigned* hist = (unsigned*)ldsbuf;
        int e0 = b * ES;
        int e1 = e0 + ES; if (e1 > E) e1 = E;
        for (int lo = 0; lo < N; lo += CS) {
            int len = N - lo; if (len > CS) len = CS;
            __syncthreads();
            for (int i = t; i < len; i += 256) hist[i] = 0;
            __syncthreads();
            for (int e = e0 + t; e < e1; e += 256) {
                unsigned dd = (unsigned)(dst[e] - lo);
                if (dd < (unsigned)len) atomicAdd(&hist[dd], 1u);
            }
            __syncthreads();
            for (int i = t; i < len; i += 256)
                ghist[(size_t)b * N + lo + i] = (u16)hist[i];
        }
        return;
    }
    // ---- gemm1 (round-11/12 passing body) ----
    __shared__ int det;
    if (t == 0) det = 0;
    __syncthreads();
    {
        int ex = (((const u16*)Av)[2 * t] >> 7) & 0xFF;
        if (ex >= 160 || ex <= 80) atomicAdd(&det, 1);
    }
    __syncthreads();
    int fl = det > 8;

    u16 (*Wt)[136] = (u16(*)[136])ldsbuf;
    for (int idx = t; idx < NOUT * 128; idx += 256) {
        int k = idx / NOUT, n = idx % NOUT;   // W row-major [128][NOUT]
        Wt[n][k] = fl ? f2bf(((const float*)W)[idx]) : ((const u16*)W)[idx];
    }
    __syncthreads();
    int wave = t >> 6, lane = t & 63;
    int m0 = (bid * 4 + wave) * 16;
    if (m0 >= M) return;
    int q = lane >> 4;
    int mr = lane & 15;

    short8 a[4];
    if (fl) {
        const float* arow = (const float*)Av + (size_t)(m0 + mr) * 128 + q * 8;
#pragma unroll
        for (int c = 0; c < 4; c++) {
            f32x4 lo = *(const f32x4*)(arow + c * 32);
            f32x4 hi = *(const f32x4*)(arow + c * 32 + 4);
            a[c][0] = (short)f2bf(lo.x); a[c][1] = (short)f2bf(lo.y);
            a[c][2] = (short)f2bf(lo.z); a[c][3] = (short)f2bf(lo.w);
            a[c][4] = (short)f2bf(hi.x); a[c][5] = (short)f2bf(hi.y);
            a[c][6] = (short)f2bf(hi.z); a[c][7] = (short)f2bf(hi.w);
        }
    } else {
        const u16* arow = (const u16*)Av + (size_t)(m0 + mr) * 128 + q * 8;
#pragma unroll
        for (int c = 0; c < 4; c++) a[c] = *(const short8*)(arow + c * 32);
    }

    f32x4 acc[NOUT / 16];
#pragma unroll
    for (int tl = 0; tl < NOUT / 16; tl++) acc[tl] = (f32x4){0.f, 0.f, 0.f, 0.f};
#pragma unroll
    for (int c = 0; c < 4; c++) {
#pragma unroll
        for (int tl = 0; tl < NOUT / 16; tl++) {
            short8 bb = *(const short8*)(&Wt[tl * 16 + mr][c * 32 + q * 8]);
            acc[tl] = __builtin_amdgcn_mfma_f32_16x16x32_bf16(a[c], bb, acc[tl], 0, 0, 0);
        }
    }
    int rbase = m0 + q * 4;   // C/D: col=lane&15, row=(lane>>4)*4+reg
#pragma unroll
    for (int tl = 0; tl < NOUT / 16; tl++) {
#pragma unroll
        for (int r = 0; r < 4; r++)
            out[(size_t)(rbase + r) * NOUT + tl * 16 + mr] = f2bf(acc[tl][r]);
    }
}

// ---- K2: per-node cross-block scan + tile scan ----------------------------
// Thread per node: serially scan the NB per-block counts (coalesced u16),
// leaving exclusive bases in ghist; degree feeds the LDS tile scan -> rowp_p
// (tile-local exclusive), sums[tile], dinv.
__global__ void k_scan2(u16* __restrict__ ghist, int* __restrict__ rowp_p,
                        int* __restrict__ sums, float* __restrict__ dinv,
                        int n, int NB) {
    __shared__ int s[256];
    int t = threadIdx.x;
    int i = blockIdx.x * 256 + t;
    int deg = 0;
    if (i < n) {
        for (int b = 0; b < NB; b++) {
            size_t idx = (size_t)b * n + i;
            int v = ghist[idx];
            ghist[idx] = (u16)deg;   // exclusive base within node bucket
            deg += v;
        }
    }
    s[t] = deg;
    __syncthreads();
    for (int off = 1; off < 256; off <<= 1) {
        int add = (t >= off) ? s[t - off] : 0;
        __syncthreads();
        s[t] += add;
        __syncthreads();
    }
    if (i < n) {
        rowp_p[i] = s[t] - deg;
        dinv[i] = rsqrtf((float)deg + 1.0f);   // deg includes self-loop
    }
    if (t == 255) sums[blockIdx.x] = s[255];
}

// ---- K3: finalize (blocks < nb) || counting-sort fill (blocks >= nb) ------
// All blocks LDS-scan the <=256 tile sums (sums[nb..255] zeroed by memset).
// Finalize: rowp[i] = rowp_p[i] + tileprefix; rowp[n] = E.
// Fill: block fb re-ranks its edge range via LDS atomics and scatters
// col[rowp_p[d] + tileprefix(d) + ghist[fb][d] + r] = src[e]. Unique slot per
// (fb,d,r); reads rowp_p only (never racing the rowp writes).
__global__ void k_fin_fill2(const int* __restrict__ rowp_p, int* __restrict__ rowp,
                            const int* __restrict__ sums, int n, int nb,
                            const int* __restrict__ src, const int* __restrict__ dst,
                            const u16* __restrict__ ghist, int* __restrict__ col,
                            int E, int N, int ES) {
    __shared__ int s[256];
    __shared__ __align__(16) char ldsbuf[50048];
    int t = threadIdx.x;
    int b = blockIdx.x;
    s[t] = sums[t];
    __syncthreads();
    for (int off = 1; off < 256; off <<= 1) {
        int add = (t >= off) ? s[t - off] : 0;
        __syncthreads();
        s[t] += add;
        __syncthreads();
    }
    __syncthreads();
    if (b < nb) {
        int prefix = (b == 0) ? 0 : s[b - 1];
        int i = b * 256 + t;
        if (i < n) rowp[i] = rowp_p[i] + prefix;
        if (i == 0) rowp[n] = E;
    } else {
        int fb = b - nb;
        unsigned* hist = (unsigned*)ldsbuf;
        int e0 = fb * ES;
        int e1 = e0 + ES; if (e1 > E) e1 = E;
        for (int lo = 0; lo < N; lo += CS) {
            int len = N - lo; if (len > CS) len = CS;
            __syncthreads();
            for (int i = t; i < len; i += 256) hist[i] = 0;
            __syncthreads();
            for (int e = e0 + t; e < e1; e += 256) {
                int d = dst[e];
                unsigned dd = (unsigned)(d - lo);
                if (dd < (unsigned)len) {
                    int r = (int)atomicAdd(&hist[dd], 1u);
                    int tile = d >> 8;
                    int pre = tile ? s[tile - 1] : 0;
                    col[rowp_p[d] + pre + (int)ghist[(size_t)fb * N + d] + r] = src[e];
                }
            }
        }
    }
}

// ---- GEMM layer 2: plain o1 @ W2 -> g2 (A always bf16; W per global flag) -
template <int NOUT>
__global__ void k_gemm_plain(const u16* __restrict__ A, const void* __restrict__ W,
                             u16* __restrict__ out, int M, const int* __restrict__ flag) {
    int fl = *flag;
    __shared__ u16 Wt[NOUT][136];
    int t = threadIdx.x;
    for (int idx = t; idx < NOUT * 128; idx += 256) {
        int k = idx / NOUT, n = idx % NOUT;
        Wt[n][k] = fl ? f2bf(((const float*)W)[idx]) : ((const u16*)W)[idx];
    }
    __syncthreads();
    int wave = t >> 6, lane = t & 63;
    int m0 = ((int)blockIdx.x * 4 + wave) * 16;
    if (m0 >= M) return;
    int q = lane >> 4;
    int mr = lane & 15;

    const u16* arow = A + (size_t)(m0 + mr) * 128 + q * 8;
    short8 a[4];
#pragma unroll
    for (int c = 0; c < 4; c++) a[c] = *(const short8*)(arow + c * 32);

    f32x4 acc[NOUT / 16];
#pragma unroll
    for (int tl = 0; tl < NOUT / 16; tl++) acc[tl] = (f32x4){0.f, 0.f, 0.f, 0.f};
#pragma unroll
    for (int c = 0; c < 4; c++) {
#pragma unroll
        for (int tl = 0; tl < NOUT / 16; tl++) {
            short8 b = *(const short8*)(&Wt[tl * 16 + mr][c * 32 + q * 8]);
            acc[tl] = __builtin_amdgcn_mfma_f32_16x16x32_bf16(a[c], b, acc[tl], 0, 0, 0);
        }
    }
    int rbase = m0 + q * 4;
#pragma unroll
    for (int tl = 0; tl < NOUT / 16; tl++) {
#pragma unroll
        for (int r = 0; r < 4; r++)
            out[(size_t)(rbase + r) * NOUT + tl * 16 + mr] = f2bf(acc[tl][r]);
    }
}

// ---- CSR gather aggregation with per-edge dinv (round-11/12 passing body) -
template <int F>
__global__ void k_agg(const u16* __restrict__ g, const int* __restrict__ rowp,
                      const int* __restrict__ col, const float* __restrict__ dinv,
                      const void* __restrict__ biasv, u16* __restrict__ outh,
                      float* __restrict__ outf, const int* __restrict__ flag,
                      int outsel, int N, int E) {
    constexpr int LPR = F / 8;      // lanes covering one feature row
    constexpr int EPW = 64 / LPR;   // edges per wave load-instruction
    int d = blockIdx.x * 4 + (threadIdx.x >> 6);
    if (d >= N) return;             // wave-uniform exit
    int lane = threadIdx.x & 63;
    int er = lane / LPR;
    int fo = (lane % LPR) * 8;

    int beg = rowp[d], end = rowp[d + 1];
    if (beg < 0) beg = 0;
    if (end > E) end = E;
    int deg = end - beg;

    float a0[8], a1[8];
#pragma unroll
    for (int j = 0; j < 8; j++) { a0[j] = 0.f; a1[j] = 0.f; }

    for (int base = 0; base < deg; base += 64) {   // deg uniform across wave
        int cnt = deg - base; if (cnt > 64) cnt = 64;
        int colv = 0;
        if (lane < cnt) {                          // predicated load only
            int s = col[beg + base + lane];
            colv = s < 0 ? 0 : (s >= N ? N - 1 : s);
        }
        int full = cnt / EPW;                      // uniform trip count
        int i = 0;
        for (; i + 2 <= full; i += 2) {
            int s0 = __shfl(colv, i * EPW + er, 64);
            int s1 = __shfl(colv, (i + 1) * EPW + er, 64);
            float d0 = dinv[s0];
            float d1 = dinv[s1];
            uint4 v0 = *(const uint4*)(g + (size_t)s0 * F + fo);
            uint4 v1 = *(const uint4*)(g + (size_t)s1 * F + fo);
            a0[0] += d0 * bflo(v0.x); a0[1] += d0 * bfhi(v0.x);
            a0[2] += d0 * bflo(v0.y); a0[3] += d0 * bfhi(v0.y);
            a0[4] += d0 * bflo(v0.z); a0[5] += d0 * bfhi(v0.z);
            a0[6] += d0 * bflo(v0.w); a0[7] += d0 * bfhi(v0.w);
            a1[0] += d1 * bflo(v1.x); a1[1] += d1 * bfhi(v1.x);
            a1[2] += d1 * bflo(v1.y); a1[3] += d1 * bfhi(v1.y);
            a1[4] += d1 * bflo(v1.z); a1[5] += d1 * bfhi(v1.z);
            a1[6] += d1 * bflo(v1.w); a1[7] += d1 * bfhi(v1.w);
        }
        if (i < full) {
            int s0 = __shfl(colv, i * EPW + er, 64);
            float d0 = dinv[s0];
            uint4 v0 = *(const uint4*)(g + (size_t)s0 * F + fo);
            a0[0] += d0 * bflo(v0.x); a0[1] += d0 * bfhi(v0.x);
            a0[2] += d0 * bflo(v0.y); a0[3] += d0 * bfhi(v0.y);
            a0[4] += d0 * bflo(v0.z); a0[5] += d0 * bfhi(v0.z);
            a0[6] += d0 * bflo(v0.w); a0[7] += d0 * bfhi(v0.w);
            i++;
        }
        int rem = cnt - full * EPW;                // leftover edges
        int s0 = __shfl(colv, (full * EPW + er) & 63, 64);   // uniform shfl
        float d0 = dinv[s0];
        if (er < rem) {                            // predicated load only
            uint4 v0 = *(const uint4*)(g + (size_t)s0 * F + fo);
            a0[0] += d0 * bflo(v0.x); a0[1] += d0 * bfhi(v0.x);
            a0[2] += d0 * bflo(v0.y); a0[3] += d0 * bfhi(v0.y);
            a0[4] += d0 * bflo(v0.z); a0[5] += d0 * bfhi(v0.z);
            a0[6] += d0 * bflo(v0.w); a0[7] += d0 * bfhi(v0.w);
        }
    }
#pragma unroll
    for (int j = 0; j < 8; j++) a0[j] += a1[j];
    // butterfly: sum across edge groups (all 64 lanes active, uniform)
#pragma unroll
    for (int off = LPR; off < 64; off <<= 1) {
#pragma unroll
        for (int j = 0; j < 8; j++) a0[j] += __shfl_xor(a0[j], off, 64);
    }

    if (lane < LPR) {   // er == 0 lanes own the result
        int fl = *flag;
        uint4 sv = *(const uint4*)(g + (size_t)d * F + fo);
        float bb[8];
        if (fl) {
            const float* bp = (const float*)biasv + fo;
            f32x4 blo = *(const f32x4*)bp;
            f32x4 bhi = *(const f32x4*)(bp + 4);
            bb[0] = blo.x; bb[1] = blo.y; bb[2] = blo.z; bb[3] = blo.w;
            bb[4] = bhi.x; bb[5] = bhi.y; bb[6] = bhi.z; bb[7] = bhi.w;
        } else {
            uint4 bv = *(const uint4*)((const u16*)biasv + fo);
            bb[0] = bflo(bv.x); bb[1] = bfhi(bv.x);
            bb[2] = bflo(bv.y); bb[3] = bfhi(bv.y);
            bb[4] = bflo(bv.z); bb[5] = bfhi(bv.z);
            bb[6] = bflo(bv.w); bb[7] = bfhi(bv.w);
        }
        float di = dinv[d];
        float sf[8] = { bflo(sv.x), bfhi(sv.x), bflo(sv.y), bfhi(sv.y),
                        bflo(sv.z), bfhi(sv.z), bflo(sv.w), bfhi(sv.w) };
        float r[8];
#pragma unroll
        for (int j = 0; j < 8; j++) {
            float v = di * (a0[j] + di * sf[j]) + bb[j];   // self-loop norm = dinv^2
            r[j] = v > 0.f ? v : 0.f;
        }
        size_t o = (size_t)d * F + fo;
        if (outsel && fl) {
            f32x4 w0 = {r[0], r[1], r[2], r[3]};
            f32x4 w1 = {r[4], r[5], r[6], r[7]};
            *(f32x4*)(outf + o) = w0;
            *(f32x4*)(outf + o + 4) = w1;
        } else {
            uint4 w;
            w.x = (unsigned)f2bf(r[0]) | ((unsigned)f2bf(r[1]) << 16);
            w.y = (unsigned)f2bf(r[2]) | ((unsigned)f2bf(r[3]) << 16);
            w.z = (unsigned)f2bf(r[4]) | ((unsigned)f2bf(r[5]) << 16);
            w.w = (unsigned)f2bf(r[6]) | ((unsigned)f2bf(r[7]) << 16);
            *(uint4*)(outh + o) = w;
        }
    }
}

// ---- launch ---------------------------------------------------------------

extern "C" void kernel_launch(void* const* d_in, const int* in_sizes, int n_in,
                              void* d_out, int out_size, void* d_ws, size_t ws_size,
                              hipStream_t stream) {
    const int N = in_sizes[0] / 128;
    const int E = in_sizes[1] / 2;
    const int* ei = (const int*)d_in[1];
    const int* src = ei;
    const int* dst = ei + E;

    char* p = (char*)d_ws;
    auto alloc = [&](size_t b) { char* r = p; p += (b + 255) & ~(size_t)255; return r; };
    int*   flag   = (int*)alloc(256);
    int*   rowp   = (int*)alloc((size_t)(N + 1) * 4);   // final
    int*   rowp_p = (int*)alloc((size_t)N * 4);         // tile-local partial
    float* dinv   = (float*)alloc((size_t)N * 4);
    int*   col    = (int*)alloc((size_t)E * 4);
    int*   sums   = (int*)alloc(256 * 4);
    u16*   ghist  = (u16*)alloc((size_t)128 * N * 2);   // per-(block,node) counts
    u16*   g1     = (u16*)alloc((size_t)N * 128 * 2);
    u16*   o1     = (u16*)alloc((size_t)N * 128 * 2);
    u16*   g2     = (u16*)alloc((size_t)N * 64 * 2);

    const int NB = 128;                  // counting-sort partitions
    int ES = (E + NB - 1) / NB;          // edges per partition
    int nb = (N + 255) / 256;
    int GB = (N / 16 + 3) / 4;           // gemm1 blocks
    int ab = (N + 3) / 4;                // one wave per node, 4 waves/block

    hipMemsetAsync(sums, 0, 1024, stream);   // sums[nb..255] must be 0

    k1_gemm_count<<<GB + NB, 256, 0, stream>>>(d_in[0], d_in[2], g1, N, GB,
                                               dst, ghist, E, N, ES, flag);
    k_scan2<<<nb, 256, 0, stream>>>(ghist, rowp_p, sums, dinv, N, NB);
    k_fin_fill2<<<nb + NB, 256, 0, stream>>>(rowp_p, rowp, sums, N, nb,
                                             src, dst, ghist, col, E, N, ES);

    k_agg<128><<<ab, 256, 0, stream>>>(g1, rowp, col, dinv, d_in[3],
                                       o1, nullptr, flag, 0, N, E);
    k_gemm_plain<64><<<GB, 256, 0, stream>>>(o1, d_in[4], g2, N, flag);
    k_agg<64><<<ab, 256, 0, stream>>>(g2, rowp, col, dinv, d_in[5],
                                      (u16*)d_out, (float*)d_out, flag, 1, N, E);
}

// Round 14
// 208.264 us; speedup vs baseline: 1.4213x; 1.4213x over previous
//
#include <hip/hip_runtime.h>

typedef unsigned short u16;
typedef __attribute__((ext_vector_type(8))) short short8;
typedef __attribute__((ext_vector_type(4))) float f32x4;

__device__ __forceinline__ float bflo(unsigned u) {
    union { unsigned u; float f; } v; v.u = u << 16; return v.f;
}
__device__ __forceinline__ float bfhi(unsigned u) {
    union { unsigned u; float f; } v; v.u = u & 0xFFFF0000u; return v.f;
}
__device__ __forceinline__ u16 f2bf(float f) {
    union { float f; unsigned u; } v; v.f = f;
    unsigned u = v.u;
    u += 0x7FFFu + ((u >> 16) & 1u);   // round-to-nearest-even
    return (u16)(u >> 16);
}

// ---- K1: gemm1 (blocks < GB, plain X@W1 -> g1) || degpos (blocks >= GB) ---
// degpos branch: R11's one-shot form (1 atomic/thread) — measured faster than
// grid-stride multi-edge (R12) and LDS counting sort (R13, occupancy hit).
__global__ void k1_gemm_deg(const void* __restrict__ Av, const void* __restrict__ W,
                            u16* __restrict__ out, int M, int GB,
                            const int* __restrict__ dst, int* __restrict__ cnt,
                            int* __restrict__ pos, int E, int* __restrict__ flag) {
    constexpr int NOUT = 128;
    int t = threadIdx.x;
    int bid = blockIdx.x;
    if (bid >= GB) {
        if (bid == GB) {
            __shared__ int c_s;
            if (t == 0) c_s = 0;
            __syncthreads();
            int c = 0;
            for (int i = t; i < 2048; i += 256) {
                int ex = (((const u16*)Av)[2 * i] >> 7) & 0xFF;
                c += (ex >= 160 || ex <= 80) ? 1 : 0;
            }
            atomicAdd(&c_s, c);
            __syncthreads();
            if (t == 0) *flag = (c_s > 64) ? 1 : 0;
        }
        int e = (bid - GB) * 256 + t;
        if (e < E) pos[e] = atomicAdd(&cnt[dst[e]], 1);
        return;
    }
    // block-local dtype detect (256 samples of x)
    __shared__ int det;
    if (t == 0) det = 0;
    __syncthreads();
    {
        int ex = (((const u16*)Av)[2 * t] >> 7) & 0xFF;
        if (ex >= 160 || ex <= 80) atomicAdd(&det, 1);
    }
    __syncthreads();
    int fl = det > 8;

    __shared__ u16 Wt[NOUT][136];
    for (int idx = t; idx < NOUT * 128; idx += 256) {
        int k = idx / NOUT, n = idx % NOUT;   // W row-major [128][NOUT]
        Wt[n][k] = fl ? f2bf(((const float*)W)[idx]) : ((const u16*)W)[idx];
    }
    __syncthreads();
    int wave = t >> 6, lane = t & 63;
    int m0 = (bid * 4 + wave) * 16;
    if (m0 >= M) return;
    int q = lane >> 4;
    int mr = lane & 15;

    short8 a[4];
    if (fl) {
        const float* arow = (const float*)Av + (size_t)(m0 + mr) * 128 + q * 8;
#pragma unroll
        for (int c = 0; c < 4; c++) {
            f32x4 lo = *(const f32x4*)(arow + c * 32);
            f32x4 hi = *(const f32x4*)(arow + c * 32 + 4);
            a[c][0] = (short)f2bf(lo.x); a[c][1] = (short)f2bf(lo.y);
            a[c][2] = (short)f2bf(lo.z); a[c][3] = (short)f2bf(lo.w);
            a[c][4] = (short)f2bf(hi.x); a[c][5] = (short)f2bf(hi.y);
            a[c][6] = (short)f2bf(hi.z); a[c][7] = (short)f2bf(hi.w);
        }
    } else {
        const u16* arow = (const u16*)Av + (size_t)(m0 + mr) * 128 + q * 8;
#pragma unroll
        for (int c = 0; c < 4; c++) a[c] = *(const short8*)(arow + c * 32);
    }

    f32x4 acc[NOUT / 16];
#pragma unroll
    for (int tl = 0; tl < NOUT / 16; tl++) acc[tl] = (f32x4){0.f, 0.f, 0.f, 0.f};
#pragma unroll
    for (int c = 0; c < 4; c++) {
#pragma unroll
        for (int tl = 0; tl < NOUT / 16; tl++) {
            short8 b = *(const short8*)(&Wt[tl * 16 + mr][c * 32 + q * 8]);
            acc[tl] = __builtin_amdgcn_mfma_f32_16x16x32_bf16(a[c], b, acc[tl], 0, 0, 0);
        }
    }
    int rbase = m0 + q * 4;   // C/D: col=lane&15, row=(lane>>4)*4+reg
#pragma unroll
    for (int tl = 0; tl < NOUT / 16; tl++) {
#pragma unroll
        for (int r = 0; r < 4; r++)
            out[(size_t)(rbase + r) * NOUT + tl * 16 + mr] = f2bf(acc[tl][r]);
    }
}

// ---- per-tile exclusive scan of cnt -> rowp_p (PARTIAL), tile sums --------
__global__ void k_scan_blocks(const int* __restrict__ cnt, int* __restrict__ rowp_p,
                              int* __restrict__ sums, int n) {
    __shared__ int s[256];
    int t = threadIdx.x;
    int i = blockIdx.x * 256 + t;
    int v = (i < n) ? cnt[i] : 0;
    s[t] = v;
    __syncthreads();
    for (int off = 1; off < 256; off <<= 1) {
        int add = (t >= off) ? s[t - off] : 0;
        __syncthreads();
        s[t] += add;
        __syncthreads();
    }
    if (i < n) rowp_p[i] = s[t] - v;
    if (t == 255) sums[blockIdx.x] = s[255];
}

// ---- merged finalize + fill (block-range split, race-free; R12 proven) ----
__global__ void k_fin_fill(const int* __restrict__ rowp_p, int* __restrict__ rowp,
                           const int* __restrict__ sums, const int* __restrict__ cnt,
                           float* __restrict__ dinv, int n, int nb,
                           const int* __restrict__ src, const int* __restrict__ dst,
                           const int* __restrict__ pos, int* __restrict__ col, int E) {
    __shared__ int s[256];
    int t = threadIdx.x;
    int b = blockIdx.x;
    s[t] = sums[t];
    __syncthreads();
    for (int off = 1; off < 256; off <<= 1) {
        int add = (t >= off) ? s[t - off] : 0;
        __syncthreads();
        s[t] += add;
        __syncthreads();
    }
    __syncthreads();
    if (b < nb) {
        int prefix = (b == 0) ? 0 : s[b - 1];
        int i = b * 256 + t;
        if (i < n) {
            rowp[i] = rowp_p[i] + prefix;
            dinv[i] = rsqrtf((float)cnt[i] + 1.0f);   // deg includes self-loop
        }
        if (i == 0) rowp[n] = E;
    } else {
        int stride = (gridDim.x - nb) * 256;
        for (int e = (b - nb) * 256 + t; e < E; e += stride) {
            int d = dst[e];
            int tile = d >> 8;
            int prefix = (tile == 0) ? 0 : s[tile - 1];
            col[rowp_p[d] + prefix + pos[e]] = src[e];
        }
    }
}

// ---- GEMM layer 2: plain o1 @ W2 -> g2 (A always bf16; W per global flag) -
template <int NOUT>
__global__ void k_gemm_plain(const u16* __restrict__ A, const void* __restrict__ W,
                             u16* __restrict__ out, int M, const int* __restrict__ flag) {
    int fl = *flag;
    __shared__ u16 Wt[NOUT][136];
    int t = threadIdx.x;
    for (int idx = t; idx < NOUT * 128; idx += 256) {
        int k = idx / NOUT, n = idx % NOUT;
        Wt[n][k] = fl ? f2bf(((const float*)W)[idx]) : ((const u16*)W)[idx];
    }
    __syncthreads();
    int wave = t >> 6, lane = t & 63;
    int m0 = ((int)blockIdx.x * 4 + wave) * 16;
    if (m0 >= M) return;
    int q = lane >> 4;
    int mr = lane & 15;

    const u16* arow = A + (size_t)(m0 + mr) * 128 + q * 8;
    short8 a[4];
#pragma unroll
    for (int c = 0; c < 4; c++) a[c] = *(const short8*)(arow + c * 32);

    f32x4 acc[NOUT / 16];
#pragma unroll
    for (int tl = 0; tl < NOUT / 16; tl++) acc[tl] = (f32x4){0.f, 0.f, 0.f, 0.f};
#pragma unroll
    for (int c = 0; c < 4; c++) {
#pragma unroll
        for (int tl = 0; tl < NOUT / 16; tl++) {
            short8 b = *(const short8*)(&Wt[tl * 16 + mr][c * 32 + q * 8]);
            acc[tl] = __builtin_amdgcn_mfma_f32_16x16x32_bf16(a[c], b, acc[tl], 0, 0, 0);
        }
    }
    int rbase = m0 + q * 4;
#pragma unroll
    for (int tl = 0; tl < NOUT / 16; tl++) {
#pragma unroll
        for (int r = 0; r < 4; r++)
            out[(size_t)(rbase + r) * NOUT + tl * 16 + mr] = f2bf(acc[tl][r]);
    }
}

// ---- CSR gather aggregation with per-edge dinv (R11/R12 passing body) -----
template <int F>
__global__ void k_agg(const u16* __restrict__ g, const int* __restrict__ rowp,
                      const int* __restrict__ col, const float* __restrict__ dinv,
                      const void* __restrict__ biasv, u16* __restrict__ outh,
                      float* __restrict__ outf, const int* __restrict__ flag,
                      int outsel, int N, int E) {
    constexpr int LPR = F / 8;      // lanes covering one feature row
    constexpr int EPW = 64 / LPR;   // edges per wave load-instruction
    int d = blockIdx.x * 4 + (threadIdx.x >> 6);
    if (d >= N) return;             // wave-uniform exit
    int lane = threadIdx.x & 63;
    int er = lane / LPR;
    int fo = (lane % LPR) * 8;

    int beg = rowp[d], end = rowp[d + 1];
    if (beg < 0) beg = 0;
    if (end > E) end = E;
    int deg = end - beg;

    float a0[8], a1[8];
#pragma unroll
    for (int j = 0; j < 8; j++) { a0[j] = 0.f; a1[j] = 0.f; }

    for (int base = 0; base < deg; base += 64) {   // deg uniform across wave
        int cnt = deg - base; if (cnt > 64) cnt = 64;
        int colv = 0;
        if (lane < cnt) {                          // predicated load only
            int s = col[beg + base + lane];
            colv = s < 0 ? 0 : (s >= N ? N - 1 : s);
        }
        int full = cnt / EPW;                      // uniform trip count
        int i = 0;
        for (; i + 2 <= full; i += 2) {
            int s0 = __shfl(colv, i * EPW + er, 64);
            int s1 = __shfl(colv, (i + 1) * EPW + er, 64);
            float d0 = dinv[s0];
            float d1 = dinv[s1];
            uint4 v0 = *(const uint4*)(g + (size_t)s0 * F + fo);
            uint4 v1 = *(const uint4*)(g + (size_t)s1 * F + fo);
            a0[0] += d0 * bflo(v0.x); a0[1] += d0 * bfhi(v0.x);
            a0[2] += d0 * bflo(v0.y); a0[3] += d0 * bfhi(v0.y);
            a0[4] += d0 * bflo(v0.z); a0[5] += d0 * bfhi(v0.z);
            a0[6] += d0 * bflo(v0.w); a0[7] += d0 * bfhi(v0.w);
            a1[0] += d1 * bflo(v1.x); a1[1] += d1 * bfhi(v1.x);
            a1[2] += d1 * bflo(v1.y); a1[3] += d1 * bfhi(v1.y);
            a1[4] += d1 * bflo(v1.z); a1[5] += d1 * bfhi(v1.z);
            a1[6] += d1 * bflo(v1.w); a1[7] += d1 * bfhi(v1.w);
        }
        if (i < full) {
            int s0 = __shfl(colv, i * EPW + er, 64);
            float d0 = dinv[s0];
            uint4 v0 = *(const uint4*)(g + (size_t)s0 * F + fo);
            a0[0] += d0 * bflo(v0.x); a0[1] += d0 * bfhi(v0.x);
            a0[2] += d0 * bflo(v0.y); a0[3] += d0 * bfhi(v0.y);
            a0[4] += d0 * bflo(v0.z); a0[5] += d0 * bfhi(v0.z);
            a0[6] += d0 * bflo(v0.w); a0[7] += d0 * bfhi(v0.w);
            i++;
        }
        int rem = cnt - full * EPW;                // leftover edges
        int s0 = __shfl(colv, (full * EPW + er) & 63, 64);   // uniform shfl
        float d0 = dinv[s0];
        if (er < rem) {                            // predicated load only
            uint4 v0 = *(const uint4*)(g + (size_t)s0 * F + fo);
            a0[0] += d0 * bflo(v0.x); a0[1] += d0 * bfhi(v0.x);
            a0[2] += d0 * bflo(v0.y); a0[3] += d0 * bfhi(v0.y);
            a0[4] += d0 * bflo(v0.z); a0[5] += d0 * bfhi(v0.z);
            a0[6] += d0 * bflo(v0.w); a0[7] += d0 * bfhi(v0.w);
        }
    }
#pragma unroll
    for (int j = 0; j < 8; j++) a0[j] += a1[j];
    // butterfly: sum across edge groups (all 64 lanes active, uniform)
#pragma unroll
    for (int off = LPR; off < 64; off <<= 1) {
#pragma unroll
        for (int j = 0; j < 8; j++) a0[j] += __shfl_xor(a0[j], off, 64);
    }

    if (lane < LPR) {   // er == 0 lanes own the result
        int fl = *flag;
        uint4 sv = *(const uint4*)(g + (size_t)d * F + fo);
        float bb[8];
        if (fl) {
            const float* bp = (const float*)biasv + fo;
            f32x4 blo = *(const f32x4*)bp;
            f32x4 bhi = *(const f32x4*)(bp + 4);
            bb[0] = blo.x; bb[1] = blo.y; bb[2] = blo.z; bb[3] = blo.w;
            bb[4] = bhi.x; bb[5] = bhi.y; bb[6] = bhi.z; bb[7] = bhi.w;
        } else {
            uint4 bv = *(const uint4*)((const u16*)biasv + fo);
            bb[0] = bflo(bv.x); bb[1] = bfhi(bv.x);
            bb[2] = bflo(bv.y); bb[3] = bfhi(bv.y);
            bb[4] = bflo(bv.z); bb[5] = bfhi(bv.z);
            bb[6] = bflo(bv.w); bb[7] = bfhi(bv.w);
        }
        float di = dinv[d];
        float sf[8] = { bflo(sv.x), bfhi(sv.x), bflo(sv.y), bfhi(sv.y),
                        bflo(sv.z), bfhi(sv.z), bflo(sv.w), bfhi(sv.w) };
        float r[8];
#pragma unroll
        for (int j = 0; j < 8; j++) {
            float v = di * (a0[j] + di * sf[j]) + bb[j];   // self-loop norm = dinv^2
            r[j] = v > 0.f ? v : 0.f;
        }
        size_t o = (size_t)d * F + fo;
        if (outsel && fl) {
            f32x4 w0 = {r[0], r[1], r[2], r[3]};
            f32x4 w1 = {r[4], r[5], r[6], r[7]};
            *(f32x4*)(outf + o) = w0;
            *(f32x4*)(outf + o + 4) = w1;
        } else {
            uint4 w;
            w.x = (unsigned)f2bf(r[0]) | ((unsigned)f2bf(r[1]) << 16);
            w.y = (unsigned)f2bf(r[2]) | ((unsigned)f2bf(r[3]) << 16);
            w.z = (unsigned)f2bf(r[4]) | ((unsigned)f2bf(r[5]) << 16);
            w.w = (unsigned)f2bf(r[6]) | ((unsigned)f2bf(r[7]) << 16);
            *(uint4*)(outh + o) = w;
        }
    }
}

// ---- launch ---------------------------------------------------------------

extern "C" void kernel_launch(void* const* d_in, const int* in_sizes, int n_in,
                              void* d_out, int out_size, void* d_ws, size_t ws_size,
                              hipStream_t stream) {
    const int N = in_sizes[0] / 128;
    const int E = in_sizes[1] / 2;
    const int* ei = (const int*)d_in[1];
    const int* src = ei;
    const int* dst = ei + E;

    char* p = (char*)d_ws;
    auto alloc = [&](size_t b) { char* r = p; p += (b + 255) & ~(size_t)255; return r; };
    int*   flag   = (int*)alloc(256);
    int*   rowp   = (int*)alloc((size_t)(N + 1) * 4);   // final
    int*   rowp_p = (int*)alloc((size_t)N * 4);         // tile-local partial
    float* dinv   = (float*)alloc((size_t)N * 4);
    int*   col    = (int*)alloc((size_t)E * 4);
    int*   cnt    = (int*)alloc((size_t)N * 4);         // contiguous w/ sums
    int*   sums   = (int*)alloc(256 * 4);
    int*   pos    = (int*)alloc((size_t)E * 4);
    u16*   g1     = (u16*)alloc((size_t)N * 128 * 2);
    u16*   o1     = (u16*)alloc((size_t)N * 128 * 2);
    u16*   g2     = (u16*)alloc((size_t)N * 64 * 2);

    int eb = (E + 255) / 256;         // one-shot degpos blocks (R11 proven)
    int nb = (N + 255) / 256;
    int GB = (N / 16 + 3) / 4;        // gemm1 blocks
    int FB = 1024;                    // fill blocks (grid-stride)
    int ab = (N + 3) / 4;             // one wave per node, 4 waves/block

    // zero cnt + sums in one call (adjacent in layout)
    hipMemsetAsync(cnt, 0, ((char*)sums - (char*)cnt) + 1024, stream);

    k1_gemm_deg<<<GB + eb, 256, 0, stream>>>(d_in[0], d_in[2], g1, N, GB,
                                             dst, cnt, pos, E, flag);
    k_scan_blocks<<<nb, 256, 0, stream>>>(cnt, rowp_p, sums, N);
    k_fin_fill<<<nb + FB, 256, 0, stream>>>(rowp_p, rowp, sums, cnt, dinv, N, nb,
                                            src, dst, pos, col, E);

    k_agg<128><<<ab, 256, 0, stream>>>(g1, rowp, col, dinv, d_in[3],
                                       o1, nullptr, flag, 0, N, E);
    k_gemm_plain<64><<<GB, 256, 0, stream>>>(o1, d_in[4], g2, N, flag);
    k_agg<64><<<ab, 256, 0, stream>>>(g2, rowp, col, dinv, d_in[5],
                                      (u16*)d_out, (float*)d_out, flag, 1, N, E);
}